// Round 1
// baseline (413.563 us; speedup 1.0000x reference)
//
#include <hip/hip_runtime.h>
#include <stdint.h>

// Spread the low 8 bits of x to stride-4 positions: bit j -> bit 4*j.
__device__ __forceinline__ uint32_t spread4(uint32_t x) {
    x = (x | (x << 12)) & 0x000F000Fu;
    x = (x | (x << 6))  & 0x03030303u;
    x = (x | (x << 3))  & 0x11111111u;
    return x;
}

// floor() on fp32 bit pattern, exactly matching the reference's bit-level spec:
//  E < 127  -> sign ? bits(-1.0f) : 0
//  E >= 150 -> u unchanged (also covers inf/nan)
//  else     -> truncate low (150-E) mantissa bits; if negative and a cleared
//              bit was set, result = bits(trunc_value - 1.0f)
__device__ __forceinline__ uint32_t floor_bits(uint32_t u) {
    uint32_t E = (u >> 23) & 0xFFu;
    uint32_t s = u >> 31;
    int sh = 150 - (int)E;
    int shc = sh < 1 ? 1 : (sh > 23 ? 23 : sh);   // clamp: only used when 127<=E<150
    uint32_t fracmask = (1u << shc) - 1u;
    uint32_t t = u & ~fracmask;
    bool hasfrac = (u & fracmask) != 0u;
    float tm1f = __uint_as_float(t) - 1.0f;       // exact in fp32 for |t| in [1, 2^23]
    uint32_t r = (s && hasfrac) ? __float_as_uint(tm1f) : t;
    if (E < 127u)  r = s ? 0xBF800000u : 0x00000000u;
    if (E >= 150u) r = u;
    return r;
}

// Input layout: flat (..., 32) float32, each element 0.0/1.0; within a value,
// index i holds bit (31-i) of the fp32 word (MSB first).
// One lane loads a float4 (4 consecutive bit-floats). A wave's 256 floats are
// exactly 8 values; value k = lane>>3 spans lanes [8k, 8k+8). Reconstruct via
// 4 ballots (one per component), then each lane emits its own 4 result bits.
__global__ __launch_bounds__(256) void spike_floor(const float4* __restrict__ in,
                                                   float4* __restrict__ out,
                                                   int n4) {
    int idx = blockIdx.x * 256 + threadIdx.x;
    if (idx >= n4) return;
    float4 v = in[idx];

    unsigned long long m0 = __ballot(v.x != 0.0f);
    unsigned long long m1 = __ballot(v.y != 0.0f);
    unsigned long long m2 = __ballot(v.z != 0.0f);
    unsigned long long m3 = __ballot(v.w != 0.0f);

    int lane = threadIdx.x & 63;
    int k8   = (lane >> 3) << 3;     // 8 * (value index within wave)

    // byte_c: bit j = value bit at position (31 - 4j - c)
    uint32_t b0 = (uint32_t)(m0 >> k8) & 0xFFu;
    uint32_t b1 = (uint32_t)(m1 >> k8) & 0xFFu;
    uint32_t b2 = (uint32_t)(m2 >> k8) & 0xFFu;
    uint32_t b3 = (uint32_t)(m3 >> k8) & 0xFFu;

    // rev8(b_c): bit m -> value bit at 4m + (3-c); spread4 then shift (3-c).
    uint32_t u = (spread4(__brev(b0) >> 24) << 3)
               | (spread4(__brev(b1) >> 24) << 2)
               | (spread4(__brev(b2) >> 24) << 1)
               |  spread4(__brev(b3) >> 24);

    uint32_t r = floor_bits(u);

    // This lane owns float offsets i0..i0+3 of its value (i0 = 4*(lane&7));
    // bit (31 - i0 - c) of r == bit (31 - c) of (r << i0).
    uint32_t rs = r << ((lane & 7) << 2);
    float4 o;
    o.x = (float)((rs >> 31) & 1u);
    o.y = (float)((rs >> 30) & 1u);
    o.z = (float)((rs >> 29) & 1u);
    o.w = (float)((rs >> 28) & 1u);
    out[idx] = o;
}

extern "C" void kernel_launch(void* const* d_in, const int* in_sizes, int n_in,
                              void* d_out, int out_size, void* d_ws, size_t ws_size,
                              hipStream_t stream) {
    const float4* in = (const float4*)d_in[0];
    float4* out = (float4*)d_out;
    int n4 = in_sizes[0] / 4;                 // 16,777,216 float4s (divisible by 256)
    int blocks = (n4 + 255) / 256;
    hipLaunchKernelGGL(spike_floor, dim3(blocks), dim3(256), 0, stream,
                       in, out, n4);
}